// Round 1
// baseline (1965.720 us; speedup 1.0000x reference)
//
#include <hip/hip_runtime.h>
#include <cstdint>

// ---------------- constants (match reference) ----------------
#define IN_DIM   128
#define HIDC     64
#define HEADS    4
#define OUT_DIM  40
#define NEG_SLOPE 0.2f
#define BN_EPS   1e-5f

// ---------------- CSR build ----------------
// edge dtype probe: if input is int64, high 32-bit words of first 1024 entries
// are all zero (values < 1e5). For int32 data those positions are real indices.
__global__ void detect_kernel(const unsigned int* __restrict__ e, int* __restrict__ flag) {
    __shared__ int any;
    if (threadIdx.x == 0) any = 0;
    __syncthreads();
    for (int i = threadIdx.x; i < 1024; i += 256)
        if (e[2 * i + 1] != 0u) any = 1;
    __syncthreads();
    if (threadIdx.x == 0) flag[0] = any ? 0 : 1;   // 1 => int64
}

__device__ __forceinline__ int load_idx(const int* ei, int is64, long long pos) {
    return is64 ? ei[2 * pos] : ei[pos];           // little-endian low word
}

__global__ void hist_kernel(const int* __restrict__ ei, const int* __restrict__ flag,
                            int* __restrict__ deg, int E, int Etot) {
    int i = blockIdx.x * 256 + threadIdx.x;
    if (i >= Etot) return;
    int is64 = flag[0];
    int dst = (i < E) ? load_idx(ei, is64, (long long)E + i) : (i - E);
    atomicAdd(&deg[dst], 1);
}

// single-block exclusive scan, in place, n up to a few hundred k
__global__ void scan_kernel(int* __restrict__ data, int n) {
    __shared__ int wsum[16];
    __shared__ int chunk_total;
    int lane = threadIdx.x & 63;
    int w = threadIdx.x >> 6;
    int carry = 0;
    for (int base = 0; base < n; base += 1024) {
        int i = base + (int)threadIdx.x;
        int v = (i < n) ? data[i] : 0;
        int x = v;
        #pragma unroll
        for (int ofs = 1; ofs < 64; ofs <<= 1) {
            int y = __shfl_up(x, ofs);
            if (lane >= ofs) x += y;
        }
        if (lane == 63) wsum[w] = x;
        __syncthreads();
        if (w == 0) {
            int s = (lane < 16) ? wsum[lane] : 0;
            #pragma unroll
            for (int ofs = 1; ofs < 16; ofs <<= 1) {
                int y = __shfl_up(s, ofs);
                if (lane >= ofs) s += y;
            }
            if (lane < 16) wsum[lane] = s;
            if (lane == 15) chunk_total = s;
        }
        __syncthreads();
        int woff = (w > 0) ? wsum[w - 1] : 0;
        if (i < n) data[i] = (x + woff) - v + carry;
        int ct = chunk_total;
        __syncthreads();
        carry += ct;
    }
}

__global__ void scatter_kernel(const int* __restrict__ ei, const int* __restrict__ flag,
                               int* __restrict__ cursor, int* __restrict__ csr,
                               int E, int Etot) {
    int i = blockIdx.x * 256 + threadIdx.x;
    if (i >= Etot) return;
    int is64 = flag[0];
    int src, dst;
    if (i < E) {
        src = load_idx(ei, is64, i);
        dst = load_idx(ei, is64, (long long)E + i);
    } else {
        src = dst = i - E;
    }
    int pos = atomicAdd(&cursor[dst], 1);
    csr[pos] = src;
}

// ---------------- GEMM: C[M][NC] = A[M][K] @ B[K][ldb] (cols bcol0..bcol0+NC) ----------------
// block = 256 threads handles 32 rows; A tile staged in LDS, broadcast reads.
__global__ void gemm_kernel(const float* __restrict__ A, const float* __restrict__ B,
                            float* __restrict__ C, int M, int K, int NC,
                            int ldb, int ldc, int bcol0, int kshift) {
    __shared__ float As[32 * 256];
    int m0 = blockIdx.x * 32;
    int t = threadIdx.x;
    int kmask = K - 1;
    for (int idx = t; idx < 32 * K; idx += 256) {
        int r = idx >> kshift;
        int m = m0 + r;
        As[idx] = (m < M) ? A[(size_t)m * K + (idx & kmask)] : 0.f;
    }
    __syncthreads();
    int tx = t & 63, ty = t >> 6;
    if (tx >= NC) return;
    float acc[8] = {0.f, 0.f, 0.f, 0.f, 0.f, 0.f, 0.f, 0.f};
    const float* Bp = B + bcol0 + tx;
    const float* Ap = &As[(ty * 8) << kshift];
    for (int k = 0; k < K; ++k) {
        float bv = Bp[(size_t)k * ldb];
        #pragma unroll
        for (int i = 0; i < 8; ++i)
            acc[i] += Ap[(i << kshift) + k] * bv;
    }
    #pragma unroll
    for (int i = 0; i < 8; ++i) {
        int m = m0 + ty * 8 + i;
        if (m < M) C[(size_t)m * ldc + tx] = acc[i];
    }
}

// ---------------- attention scalars: a_src[n] = h[n]·att_s, a_dst[n] = h[n]·att_d ----------------
__global__ void attn_dot_kernel(const float* __restrict__ h, const float* __restrict__ att_s,
                                const float* __restrict__ att_d, float* __restrict__ a_s,
                                float* __restrict__ a_d, int C, int N) {
    int wid = (blockIdx.x * blockDim.x + threadIdx.x) >> 6;
    int lane = threadIdx.x & 63;
    if (wid >= N) return;
    float v = (lane < C) ? h[(size_t)wid * C + lane] : 0.f;
    float ps = (lane < C) ? v * att_s[lane] : 0.f;
    float pd = (lane < C) ? v * att_d[lane] : 0.f;
    #pragma unroll
    for (int o = 32; o; o >>= 1) {
        ps += __shfl_xor(ps, o);
        pd += __shfl_xor(pd, o);
    }
    if (lane == 0) { a_s[wid] = ps; a_d[wid] = pd; }
}

// ---------------- aggregation: one wave per destination node ----------------
// EP==0: out[n][c] = ELU(BN(acc + bias))        (bias/bn ptrs pre-offset by col0)
// EP==1: out row = log_softmax(acc + bias)
template <int EP>
__global__ void aggregate_kernel(const int* __restrict__ off, const int* __restrict__ csr,
                                 const float* __restrict__ a_s, const float* __restrict__ a_d,
                                 const float* __restrict__ h, int C, int N,
                                 float* __restrict__ out, int ldo,
                                 const float* __restrict__ bias,
                                 const float* __restrict__ bng, const float* __restrict__ bnb,
                                 const float* __restrict__ bnm, const float* __restrict__ bnv) {
    int wid = (blockIdx.x * blockDim.x + threadIdx.x) >> 6;
    int lane = threadIdx.x & 63;
    if (wid >= N) return;
    int beg = off[wid], end = off[wid + 1];
    float ad = a_d[wid];

    // pass 1: neighborhood max of leaky_relu(a_src+a_dst)
    float m = -INFINITY;
    for (int j = beg + lane; j < end; j += 64) {
        float e = a_s[csr[j]] + ad;
        e = (e > 0.f) ? e : NEG_SLOPE * e;
        m = fmaxf(m, e);
    }
    #pragma unroll
    for (int o = 32; o; o >>= 1) m = fmaxf(m, __shfl_xor(m, o));

    // pass 2: sum of exp
    float ss = 0.f;
    for (int j = beg + lane; j < end; j += 64) {
        float e = a_s[csr[j]] + ad;
        e = (e > 0.f) ? e : NEG_SLOPE * e;
        ss += __expf(e - m);
    }
    #pragma unroll
    for (int o = 32; o; o >>= 1) ss += __shfl_xor(ss, o);
    float inv = 1.f / (ss + 1e-16f);

    // pass 3: weighted sum of h[src] rows (lane = channel)
    float acc = 0.f;
    for (int j = beg; j < end; ++j) {
        int s = csr[j];
        float e = a_s[s] + ad;                   // broadcast loads
        e = (e > 0.f) ? e : NEG_SLOPE * e;
        float alpha = __expf(e - m) * inv;
        float hv = (lane < C) ? h[(size_t)s * C + lane] : 0.f;
        acc += alpha * hv;
    }

    if (EP == 0) {
        if (lane < C) {
            float val = acc + bias[lane];
            val = (val - bnm[lane]) * (bng[lane] * rsqrtf(bnv[lane] + BN_EPS)) + bnb[lane];
            val = (val > 0.f) ? val : expm1f(val);
            out[(size_t)wid * ldo + lane] = val;
        }
    } else {
        float val = (lane < C) ? acc + bias[lane] : -INFINITY;
        float mx = val;
        #pragma unroll
        for (int o = 32; o; o >>= 1) mx = fmaxf(mx, __shfl_xor(mx, o));
        float ex = (lane < C) ? __expf(val - mx) : 0.f;
        float s2 = ex;
        #pragma unroll
        for (int o = 32; o; o >>= 1) s2 += __shfl_xor(s2, o);
        if (lane < C) out[(size_t)wid * ldo + lane] = val - mx - logf(s2);
    }
}

// ---------------- host ----------------
extern "C" void kernel_launch(void* const* d_in, const int* in_sizes, int n_in,
                              void* d_out, int out_size, void* d_ws, size_t ws_size,
                              hipStream_t stream) {
    const float* x       = (const float*)d_in[0];
    const int*   ei      = (const int*)d_in[1];
    const float* W1      = (const float*)d_in[2];
    const float* att_s1  = (const float*)d_in[3];
    const float* att_d1  = (const float*)d_in[4];
    const float* b1      = (const float*)d_in[5];
    const float* bn1g    = (const float*)d_in[6];
    const float* bn1b    = (const float*)d_in[7];
    const float* bn1m    = (const float*)d_in[8];
    const float* bn1v    = (const float*)d_in[9];
    const float* W2      = (const float*)d_in[10];
    const float* att_s2  = (const float*)d_in[11];
    const float* att_d2  = (const float*)d_in[12];
    const float* b2      = (const float*)d_in[13];
    const float* bn2g    = (const float*)d_in[14];
    const float* bn2b    = (const float*)d_in[15];
    const float* bn2m    = (const float*)d_in[16];
    const float* bn2v    = (const float*)d_in[17];
    const float* W3      = (const float*)d_in[18];
    const float* att_s3  = (const float*)d_in[19];
    const float* att_d3  = (const float*)d_in[20];
    const float* b3      = (const float*)d_in[21];

    const int N    = in_sizes[0] / IN_DIM;       // 100000
    const int E    = in_sizes[1] / 2;            // 1600000
    const int Etot = E + N;

    // workspace layout (4-byte units)
    int*   wsi = (int*)d_ws;
    float* wsf = (float*)d_ws;
    size_t p = 0;
    int*   off    = wsi + p; p += (size_t)N + 4;
    int*   cursor = wsi + p; p += (size_t)N;
    int*   flag   = wsi + p; p += 4;
    int*   csr    = wsi + p; p += (size_t)Etot;
    float* a_s    = wsf + p; p += (size_t)N;
    float* a_d    = wsf + p; p += (size_t)N;
    float* hbuf   = wsf + p; p += (size_t)N * 64;
    float* act    = wsf + p; p += (size_t)N * 256;
    if (ws_size < p * 4) return;                 // insufficient scratch: bail

    float* outp = (float*)d_out;

    // ---- CSR build ----
    hipMemsetAsync(off, 0, ((size_t)N + 1) * sizeof(int), stream);
    detect_kernel<<<1, 256, 0, stream>>>((const unsigned int*)ei, flag);
    {
        int blocks = (Etot + 255) / 256;
        hist_kernel<<<blocks, 256, 0, stream>>>(ei, flag, off, E, Etot);
        scan_kernel<<<1, 1024, 0, stream>>>(off, N + 1);
        hipMemcpyAsync(cursor, off, (size_t)N * sizeof(int), hipMemcpyDeviceToDevice, stream);
        scatter_kernel<<<blocks, 256, 0, stream>>>(ei, flag, cursor, csr, E, Etot);
    }

    const int gemm_blocks = (N + 31) / 32;
    const int node_blocks = (N + 3) / 4;         // 4 waves/block, 1 wave per node

    // ---- layer 1 (4 heads, concat) : act[N][256] ----
    for (int hd = 0; hd < HEADS; ++hd) {
        gemm_kernel<<<gemm_blocks, 256, 0, stream>>>(x, W1, hbuf, N, IN_DIM, HIDC,
                                                     HEADS * HIDC, HIDC, hd * HIDC, 7);
        attn_dot_kernel<<<node_blocks, 256, 0, stream>>>(hbuf, att_s1 + hd * HIDC,
                                                         att_d1 + hd * HIDC, a_s, a_d, HIDC, N);
        aggregate_kernel<0><<<node_blocks, 256, 0, stream>>>(
            off, csr, a_s, a_d, hbuf, HIDC, N, act + hd * HIDC, HEADS * HIDC,
            b1 + hd * HIDC, bn1g + hd * HIDC, bn1b + hd * HIDC, bn1m + hd * HIDC, bn1v + hd * HIDC);
    }

    // ---- layer 2 (1 head) : act2[N][64] (reuses act buffer) ----
    gemm_kernel<<<gemm_blocks, 256, 0, stream>>>(act, W2, hbuf, N, HEADS * HIDC, HIDC,
                                                 HIDC, HIDC, 0, 8);
    attn_dot_kernel<<<node_blocks, 256, 0, stream>>>(hbuf, att_s2, att_d2, a_s, a_d, HIDC, N);
    aggregate_kernel<0><<<node_blocks, 256, 0, stream>>>(
        off, csr, a_s, a_d, hbuf, HIDC, N, act, HIDC, b2, bn2g, bn2b, bn2m, bn2v);

    // ---- layer 3 (1 head, 40 out) + log_softmax -> d_out ----
    gemm_kernel<<<gemm_blocks, 256, 0, stream>>>(act, W3, hbuf, N, HIDC, OUT_DIM,
                                                 OUT_DIM, OUT_DIM, 0, 6);
    attn_dot_kernel<<<node_blocks, 256, 0, stream>>>(hbuf, att_s3, att_d3, a_s, a_d, OUT_DIM, N);
    aggregate_kernel<1><<<node_blocks, 256, 0, stream>>>(
        off, csr, a_s, a_d, hbuf, OUT_DIM, N, outp, OUT_DIM, b3,
        nullptr, nullptr, nullptr, nullptr);
}

// Round 2
// 1271.120 us; speedup vs baseline: 1.5464x; 1.5464x over previous
//
#include <hip/hip_runtime.h>
#include <cstdint>

#define IN_DIM   128
#define HIDC     64
#define HEADS    4
#define OUT_DIM  40
#define NEG_SLOPE 0.2f
#define BN_EPS   1e-5f

typedef unsigned short ushortt;

__device__ __forceinline__ float bfval(ushortt u) {
    return __uint_as_float(((unsigned)u) << 16);
}
__device__ __forceinline__ ushortt f2bf(float f) {
    unsigned u = __float_as_uint(f);
    u += 0x7fffu + ((u >> 16) & 1u);
    return (ushortt)(u >> 16);
}

// ---------------- CSR build ----------------
__global__ void detect_kernel(const unsigned int* __restrict__ e, int* __restrict__ flag) {
    __shared__ int any;
    if (threadIdx.x == 0) any = 0;
    __syncthreads();
    for (int i = threadIdx.x; i < 1024; i += 256)
        if (e[2 * i + 1] != 0u) any = 1;
    __syncthreads();
    if (threadIdx.x == 0) flag[0] = any ? 0 : 1;   // 1 => int64
}

__device__ __forceinline__ int load_idx(const int* ei, int is64, long long pos) {
    return is64 ? ei[2 * pos] : ei[pos];
}

__global__ void hist_kernel(const int* __restrict__ ei, const int* __restrict__ flag,
                            int* __restrict__ deg, int E, int Etot) {
    int i = blockIdx.x * 256 + threadIdx.x;
    if (i >= Etot) return;
    int is64 = flag[0];
    int dst = (i < E) ? load_idx(ei, is64, (long long)E + i) : (i - E);
    atomicAdd(&deg[dst], 1);
}

__global__ void scan_kernel(int* __restrict__ data, int n) {
    __shared__ int wsum[16];
    __shared__ int chunk_total;
    int lane = threadIdx.x & 63;
    int w = threadIdx.x >> 6;
    int carry = 0;
    for (int base = 0; base < n; base += 1024) {
        int i = base + (int)threadIdx.x;
        int v = (i < n) ? data[i] : 0;
        int x = v;
        #pragma unroll
        for (int ofs = 1; ofs < 64; ofs <<= 1) {
            int y = __shfl_up(x, ofs);
            if (lane >= ofs) x += y;
        }
        if (lane == 63) wsum[w] = x;
        __syncthreads();
        if (w == 0) {
            int s = (lane < 16) ? wsum[lane] : 0;
            #pragma unroll
            for (int ofs = 1; ofs < 16; ofs <<= 1) {
                int y = __shfl_up(s, ofs);
                if (lane >= ofs) s += y;
            }
            if (lane < 16) wsum[lane] = s;
            if (lane == 15) chunk_total = s;
        }
        __syncthreads();
        int woff = (w > 0) ? wsum[w - 1] : 0;
        if (i < n) data[i] = (x + woff) - v + carry;
        int ct = chunk_total;
        __syncthreads();
        carry += ct;
    }
}

__global__ void scatter_kernel(const int* __restrict__ ei, const int* __restrict__ flag,
                               int* __restrict__ cursor, int* __restrict__ csr,
                               int E, int Etot) {
    int i = blockIdx.x * 256 + threadIdx.x;
    if (i >= Etot) return;
    int is64 = flag[0];
    int src, dst;
    if (i < E) {
        src = load_idx(ei, is64, i);
        dst = load_idx(ei, is64, (long long)E + i);
    } else {
        src = dst = i - E;
    }
    int pos = atomicAdd(&cursor[dst], 1);
    csr[pos] = src;
}

// ---------------- GEMM layer1: x[N][128] @ W1[128][256] -> hB bf16 [N][256], a_s4/a_d4 [N][4] ----------------
__launch_bounds__(256)
__global__ void gemm1_kernel(const float* __restrict__ A, const float* __restrict__ W,
                             const float* __restrict__ atts, const float* __restrict__ attd,
                             ushortt* __restrict__ hB, float* __restrict__ a_s4,
                             float* __restrict__ a_d4, int N) {
    __shared__ float As[32 * 128];          // 16 KB
    int m0 = blockIdx.x * 32;
    int t = threadIdx.x;
    for (int idx = t; idx < 32 * 128; idx += 256) {
        int r = idx >> 7, c = idx & 127;
        int mm = m0 + r;
        As[idx] = (mm < N) ? A[(size_t)mm * 128 + c] : 0.f;
    }
    __syncthreads();
    int tx = t & 63, ty = t >> 6;
    float acc[8][4] = {};
    const float* Ap = &As[(ty * 8) << 7];
    #pragma unroll 2
    for (int k = 0; k < 128; ++k) {
        float b0 = W[k * 256 + tx];
        float b1 = W[k * 256 + tx + 64];
        float b2 = W[k * 256 + tx + 128];
        float b3 = W[k * 256 + tx + 192];
        #pragma unroll
        for (int i = 0; i < 8; ++i) {
            float a = Ap[(i << 7) + k];
            acc[i][0] += a * b0; acc[i][1] += a * b1;
            acc[i][2] += a * b2; acc[i][3] += a * b3;
        }
    }
    #pragma unroll
    for (int i = 0; i < 8; ++i) {
        int mm = m0 + ty * 8 + i;
        if (mm < N) {
            #pragma unroll
            for (int c = 0; c < 4; ++c) {
                float v = acc[i][c];
                hB[(size_t)mm * 256 + c * 64 + tx] = f2bf(v);
                float ps = v * atts[c * 64 + tx];
                float pd = v * attd[c * 64 + tx];
                #pragma unroll
                for (int o = 32; o; o >>= 1) { ps += __shfl_xor(ps, o); pd += __shfl_xor(pd, o); }
                if (tx == 0) { a_s4[(size_t)mm * 4 + c] = ps; a_d4[(size_t)mm * 4 + c] = pd; }
            }
        }
    }
}

// ---------------- GEMM layers 2/3: A[N][K] @ W[K][NC] -> hB bf16 [N][NC], a_s/a_d [N] ----------------
template <int K, int NC>
__launch_bounds__(256)
__global__ void gemm_attn_kernel(const float* __restrict__ A, const float* __restrict__ W,
                                 const float* __restrict__ atts, const float* __restrict__ attd,
                                 ushortt* __restrict__ hB, float* __restrict__ a_s,
                                 float* __restrict__ a_d, int N) {
    __shared__ float As[32 * K];
    int m0 = blockIdx.x * 32;
    int t = threadIdx.x;
    for (int idx = t; idx < 32 * K; idx += 256) {
        int r = idx / K, c = idx % K;       // K pow2 -> shifts
        int mm = m0 + r;
        As[idx] = (mm < N) ? A[(size_t)mm * K + c] : 0.f;
    }
    __syncthreads();
    int tx = t & 63, ty = t >> 6;
    float acc[8] = {};
    const float* Ap = &As[(ty * 8) * K];
    #pragma unroll 2
    for (int k = 0; k < K; ++k) {
        float bv = (tx < NC) ? W[k * NC + tx] : 0.f;
        #pragma unroll
        for (int i = 0; i < 8; ++i) acc[i] += Ap[i * K + k] * bv;
    }
    #pragma unroll
    for (int i = 0; i < 8; ++i) {
        int mm = m0 + ty * 8 + i;
        if (mm < N) {
            if (tx < NC) hB[(size_t)mm * NC + tx] = f2bf(acc[i]);
            float ps = (tx < NC) ? acc[i] * atts[tx] : 0.f;
            float pd = (tx < NC) ? acc[i] * attd[tx] : 0.f;
            #pragma unroll
            for (int o = 32; o; o >>= 1) { ps += __shfl_xor(ps, o); pd += __shfl_xor(pd, o); }
            if (tx == 0) { a_s[mm] = ps; a_d[mm] = pd; }
        }
    }
}

// ---------------- PV chunk: broadcast (s, alpha) from lanes, 8 independent gathers per iter ----------------
__device__ __forceinline__ float pv_chunk(int sreg, float al, int n,
                                          const ushortt* __restrict__ hB, int coff,
                                          int stride, bool active) {
    float acc = 0.f;
    for (int jj = 0; jj < n; jj += 8) {
        int rem = n - jj;
        int sv[8]; float av[8]; float hv[8];
        #pragma unroll
        for (int k = 0; k < 8; ++k) {
            sv[k] = __shfl(sreg, jj + k);
            av[k] = __shfl(al,   jj + k);
        }
        #pragma unroll
        for (int k = 0; k < 8; ++k) {
            if (k < rem && active) hv[k] = bfval(hB[(size_t)sv[k] * stride + coff]);
            else hv[k] = 0.f;
        }
        #pragma unroll
        for (int k = 0; k < 8; ++k)
            if (k < rem) acc += av[k] * hv[k];
    }
    return acc;
}

// ---------------- layer-1 aggregate: block = node, wave = head ----------------
__launch_bounds__(256)
__global__ void agg1_kernel(const int* __restrict__ off, const int* __restrict__ csr,
                            const float* __restrict__ a_s4, const float* __restrict__ a_d4,
                            const ushortt* __restrict__ hB, float* __restrict__ act,
                            const float* __restrict__ bias,
                            const float* __restrict__ bng, const float* __restrict__ bnb,
                            const float* __restrict__ bnm, const float* __restrict__ bnv, int N) {
    int node = blockIdx.x;
    if (node >= N) return;
    int head = threadIdx.x >> 6, lane = threadIdx.x & 63;
    int beg = off[node], end = off[node + 1];
    int deg = end - beg;
    float ad = a_d4[(size_t)node * 4 + head];
    int n0 = deg < 64 ? deg : 64;
    int sreg = 0; float e0 = -INFINITY;
    if (lane < n0) {
        sreg = csr[beg + lane];
        float v = a_s4[(size_t)sreg * 4 + head] + ad;
        e0 = v > 0.f ? v : NEG_SLOPE * v;
    }
    float m = e0;
    if (deg > 64)
        for (int j = beg + 64 + lane; j < end; j += 64) {
            int s = csr[j];
            float v = a_s4[(size_t)s * 4 + head] + ad;
            v = v > 0.f ? v : NEG_SLOPE * v;
            m = fmaxf(m, v);
        }
    #pragma unroll
    for (int o = 32; o; o >>= 1) m = fmaxf(m, __shfl_xor(m, o));
    float ex0 = (lane < n0) ? __expf(e0 - m) : 0.f;
    float ss = ex0;
    if (deg > 64)
        for (int j = beg + 64 + lane; j < end; j += 64) {
            int s = csr[j];
            float v = a_s4[(size_t)s * 4 + head] + ad;
            v = v > 0.f ? v : NEG_SLOPE * v;
            ss += __expf(v - m);
        }
    #pragma unroll
    for (int o = 32; o; o >>= 1) ss += __shfl_xor(ss, o);
    float inv = 1.f / (ss + 1e-16f);
    int coff = head * 64 + lane;
    float acc = pv_chunk(sreg, ex0 * inv, n0, hB, coff, 256, true);
    if (deg > 64)
        for (int base = beg + 64; base < end; base += 64) {
            int n = (end - base < 64) ? end - base : 64;
            int s = 0; float al = 0.f;
            if (lane < n) {
                s = csr[base + lane];
                float v = a_s4[(size_t)s * 4 + head] + ad;
                v = v > 0.f ? v : NEG_SLOPE * v;
                al = __expf(v - m) * inv;
            }
            acc += pv_chunk(s, al, n, hB, coff, 256, true);
        }
    int ch = head * 64 + lane;
    float val = acc + bias[ch];
    val = (val - bnm[ch]) * (bng[ch] * rsqrtf(bnv[ch] + BN_EPS)) + bnb[ch];
    val = val > 0.f ? val : expm1f(val);
    act[(size_t)node * 256 + ch] = val;
}

// ---------------- single-head aggregate (layers 2/3), wave = node ----------------
// EP==0: ELU(BN(acc+bias)) -> out[node][C]; EP==1: log_softmax(acc+bias)
template <int EP, int C>
__launch_bounds__(256)
__global__ void agg_single_kernel(const int* __restrict__ off, const int* __restrict__ csr,
                                  const float* __restrict__ a_s, const float* __restrict__ a_d,
                                  const ushortt* __restrict__ hB, float* __restrict__ out,
                                  const float* __restrict__ bias,
                                  const float* __restrict__ bng, const float* __restrict__ bnb,
                                  const float* __restrict__ bnm, const float* __restrict__ bnv, int N) {
    int node = blockIdx.x * 4 + (threadIdx.x >> 6);
    int lane = threadIdx.x & 63;
    if (node >= N) return;
    int beg = off[node], end = off[node + 1];
    int deg = end - beg;
    float ad = a_d[node];
    int n0 = deg < 64 ? deg : 64;
    int sreg = 0; float e0 = -INFINITY;
    if (lane < n0) {
        sreg = csr[beg + lane];
        float v = a_s[sreg] + ad;
        e0 = v > 0.f ? v : NEG_SLOPE * v;
    }
    float m = e0;
    if (deg > 64)
        for (int j = beg + 64 + lane; j < end; j += 64) {
            float v = a_s[csr[j]] + ad;
            v = v > 0.f ? v : NEG_SLOPE * v;
            m = fmaxf(m, v);
        }
    #pragma unroll
    for (int o = 32; o; o >>= 1) m = fmaxf(m, __shfl_xor(m, o));
    float ex0 = (lane < n0) ? __expf(e0 - m) : 0.f;
    float ss = ex0;
    if (deg > 64)
        for (int j = beg + 64 + lane; j < end; j += 64) {
            float v = a_s[csr[j]] + ad;
            v = v > 0.f ? v : NEG_SLOPE * v;
            ss += __expf(v - m);
        }
    #pragma unroll
    for (int o = 32; o; o >>= 1) ss += __shfl_xor(ss, o);
    float inv = 1.f / (ss + 1e-16f);
    bool active = lane < C;
    float acc = pv_chunk(sreg, ex0 * inv, n0, hB, lane, C, active);
    if (deg > 64)
        for (int base = beg + 64; base < end; base += 64) {
            int n = (end - base < 64) ? end - base : 64;
            int s = 0; float al = 0.f;
            if (lane < n) {
                s = csr[base + lane];
                float v = a_s[s] + ad;
                v = v > 0.f ? v : NEG_SLOPE * v;
                al = __expf(v - m) * inv;
            }
            acc += pv_chunk(s, al, n, hB, lane, C, active);
        }
    if (EP == 0) {
        if (active) {
            float val = acc + bias[lane];
            val = (val - bnm[lane]) * (bng[lane] * rsqrtf(bnv[lane] + BN_EPS)) + bnb[lane];
            val = val > 0.f ? val : expm1f(val);
            out[(size_t)node * C + lane] = val;
        }
    } else {
        float val = active ? acc + bias[lane] : -INFINITY;
        float mx = val;
        #pragma unroll
        for (int o = 32; o; o >>= 1) mx = fmaxf(mx, __shfl_xor(mx, o));
        float ex = active ? __expf(val - mx) : 0.f;
        float s2 = ex;
        #pragma unroll
        for (int o = 32; o; o >>= 1) s2 += __shfl_xor(s2, o);
        if (active) out[(size_t)node * C + lane] = val - mx - logf(s2);
    }
}

// ---------------- host ----------------
extern "C" void kernel_launch(void* const* d_in, const int* in_sizes, int n_in,
                              void* d_out, int out_size, void* d_ws, size_t ws_size,
                              hipStream_t stream) {
    const float* x      = (const float*)d_in[0];
    const int*   ei     = (const int*)d_in[1];
    const float* W1     = (const float*)d_in[2];
    const float* att_s1 = (const float*)d_in[3];
    const float* att_d1 = (const float*)d_in[4];
    const float* b1     = (const float*)d_in[5];
    const float* bn1g   = (const float*)d_in[6];
    const float* bn1b   = (const float*)d_in[7];
    const float* bn1m   = (const float*)d_in[8];
    const float* bn1v   = (const float*)d_in[9];
    const float* W2     = (const float*)d_in[10];
    const float* att_s2 = (const float*)d_in[11];
    const float* att_d2 = (const float*)d_in[12];
    const float* b2     = (const float*)d_in[13];
    const float* bn2g   = (const float*)d_in[14];
    const float* bn2b   = (const float*)d_in[15];
    const float* bn2m   = (const float*)d_in[16];
    const float* bn2v   = (const float*)d_in[17];
    const float* W3     = (const float*)d_in[18];
    const float* att_s3 = (const float*)d_in[19];
    const float* att_d3 = (const float*)d_in[20];
    const float* b3     = (const float*)d_in[21];

    const int N    = in_sizes[0] / IN_DIM;
    const int E    = in_sizes[1] / 2;
    const int Etot = E + N;

    int*   wsi = (int*)d_ws;
    float* wsf = (float*)d_ws;
    size_t p = 0;
    int*   off    = wsi + p; p += (size_t)N + 4;
    int*   cursor = wsi + p; p += (size_t)N;
    int*   flag   = wsi + p; p += 4;
    int*   csr    = wsi + p; p += (size_t)Etot;
    float* a_s    = wsf + p; p += (size_t)N * 4;
    float* a_d    = wsf + p; p += (size_t)N * 4;
    ushortt* hB   = (ushortt*)(wsf + p); p += (size_t)N * 128;   // N*256 bf16
    float* act    = wsf + p; p += (size_t)N * 256;
    if (ws_size < p * 4) return;

    float* outp = (float*)d_out;

    // ---- CSR build ----
    hipMemsetAsync(off, 0, ((size_t)N + 1) * sizeof(int), stream);
    detect_kernel<<<1, 256, 0, stream>>>((const unsigned int*)ei, flag);
    {
        int blocks = (Etot + 255) / 256;
        hist_kernel<<<blocks, 256, 0, stream>>>(ei, flag, off, E, Etot);
        scan_kernel<<<1, 1024, 0, stream>>>(off, N + 1);
        hipMemcpyAsync(cursor, off, (size_t)N * sizeof(int), hipMemcpyDeviceToDevice, stream);
        scatter_kernel<<<blocks, 256, 0, stream>>>(ei, flag, cursor, csr, E, Etot);
    }

    const int gemm_blocks = (N + 31) / 32;
    const int node_blocks4 = (N + 3) / 4;

    // ---- layer 1 (4 heads fused) ----
    gemm1_kernel<<<gemm_blocks, 256, 0, stream>>>(x, W1, att_s1, att_d1, hB, a_s, a_d, N);
    agg1_kernel<<<N, 256, 0, stream>>>(off, csr, a_s, a_d, hB, act,
                                       b1, bn1g, bn1b, bn1m, bn1v, N);

    // ---- layer 2 ----
    gemm_attn_kernel<256, 64><<<gemm_blocks, 256, 0, stream>>>(act, W2, att_s2, att_d2,
                                                               hB, a_s, a_d, N);
    agg_single_kernel<0, 64><<<node_blocks4, 256, 0, stream>>>(off, csr, a_s, a_d, hB, act,
                                                               b2, bn2g, bn2b, bn2m, bn2v, N);

    // ---- layer 3 + log_softmax ----
    gemm_attn_kernel<64, 40><<<gemm_blocks, 256, 0, stream>>>(act, W3, att_s3, att_d3,
                                                              hB, a_s, a_d, N);
    agg_single_kernel<1, 40><<<node_blocks4, 256, 0, stream>>>(off, csr, a_s, a_d, hB, outp,
                                                               b3, nullptr, nullptr, nullptr, nullptr, N);
}